// Round 9
// baseline (4260.243 us; speedup 1.0000x reference)
//
#include <hip/hip_runtime.h>
#include <cmath>

// ---------------- problem constants ----------------
#define NBATCH 64
#define NQB    16            // batches per quarter
#define TLEN   8192
#define LA     4096
#define LB     2048
#define HID    128
#define HHALF  64
#define RESCH  32
#define EMB    64
#define NCODE  512
#define NTOK   (NBATCH * LB)   // 131072

// ---------------- f64 weight region (double offsets within dws) ----------------
#define DW_MEAN 0      // 64
#define DW_RSTD 64     // 64
#define DW_W1   128    // 256
#define DW_B1   384    // 64
#define DW_W2   448    // 32768
#define DW_B2   33216  // 128
#define DW_W3   33344  // 49152
#define DW_B3   82496  // 128
#define DW_RW1  82624  // 24576
#define DW_RW2  107200 // 8192
#define DW_PW   115392 // 8192
#define DW_PB   123584 // 64
// end: 123648 doubles = 989,184 bytes (< 2 MiB header)

// ---------------- f32 small region (float offsets within ws) ----------------
#define WS_FMEAN 327680
#define WS_FSTD  327744
#define WS_CNORM 327808   // 512
#define WS_CNT   328320   // 512
#define WS_SSE   328832   // 1

// ---------------- big buffers (byte offsets; total ≤ 136.4 MB, ws ≥ 151.0 MB known) ----------------
#define OFF_QUANT 2097152ull        // f32 [64][64][2048]  = 33,554,432
#define OFF_D2Q   35651584ull       // f64 [16][128][2048] = 33,554,432
#define OFF_D3Q   69206016ull       // f64 [16][128][2048] = 33,554,432
#define OFF_S64Q  102760448ull      // f64 [16][32][2048]  =  8,388,608
#define OFF_Z64Q  111149056ull      // f64 [16][64][2048]  = 16,777,216  (end 127,926,272)
// decoder phase (quarter buffers dead):
#define OFF_A32   69206016ull       // f32 [64][128][2048] = 67,108,864  (end 136,314,880)
#define OFF_S32   2097152ull        // f32 [64][32][2048]  = 16,777,216  (QUANT dead)
#define OFF_B32   2097152ull        // f32 [64][64][4096]  = 67,108,864  (S32 dead; end 69,206,016)

// ================= tiny kernels =================

__global__ __launch_bounds__(1024) void zero_kernel(float* p, int n) {
    int i = blockIdx.x * 1024 + threadIdx.x;
    if (i < n) p[i] = 0.f;
}

__global__ __launch_bounds__(256) void cvt_kernel(const float* __restrict__ src,
                                                  double* __restrict__ dst, int n) {
    int i = blockIdx.x * 256 + threadIdx.x;
    if (i < n) dst[i] = (double)src[i];
}

// ||c||^2 in f32, numpy-pairwise style: squares (rounded muls) then 8-partial sum
__global__ __launch_bounds__(256) void cnorm_kernel(const float* __restrict__ cb,
                                                    float* __restrict__ cnorm) {
    int k = blockIdx.x * 256 + threadIdx.x;
    if (k < NCODE) {
        float p0=0,p1=0,p2=0,p3=0,p4=0,p5=0,p6=0,p7=0;
        const float* cp = cb + k * EMB;
        #pragma unroll
        for (int d = 0; d < EMB; d += 8) {
            p0 = __fadd_rn(p0, __fmul_rn(cp[d],   cp[d]));
            p1 = __fadd_rn(p1, __fmul_rn(cp[d+1], cp[d+1]));
            p2 = __fadd_rn(p2, __fmul_rn(cp[d+2], cp[d+2]));
            p3 = __fadd_rn(p3, __fmul_rn(cp[d+3], cp[d+3]));
            p4 = __fadd_rn(p4, __fmul_rn(cp[d+4], cp[d+4]));
            p5 = __fadd_rn(p5, __fmul_rn(cp[d+5], cp[d+5]));
            p6 = __fadd_rn(p6, __fmul_rn(cp[d+6], cp[d+6]));
            p7 = __fadd_rn(p7, __fmul_rn(cp[d+7], cp[d+7]));
        }
        float s01 = __fadd_rn(p0, p1), s23 = __fadd_rn(p2, p3);
        float s45 = __fadd_rn(p4, p5), s67 = __fadd_rn(p6, p7);
        cnorm[k] = __fadd_rn(__fadd_rn(s01, s23), __fadd_rn(s45, s67));
    }
}

// per-batch mean/std over T=8192, f64
__global__ __launch_bounds__(256) void stats_kernel(const float* __restrict__ x,
                                                    double* dws, float* ws) {
    __shared__ float sx[TLEN];
    __shared__ double red[256];
    const int b = blockIdx.x, t = threadIdx.x;
    const float* xb = x + (size_t)b * TLEN;
    double s = 0.0;
    for (int i = t; i < TLEN; i += 256) { float v = xb[i]; sx[i] = v; s += (double)v; }
    red[t] = s; __syncthreads();
    for (int st = 128; st > 0; st >>= 1) { if (t < st) red[t] += red[t + st]; __syncthreads(); }
    double mean = red[0] / (double)TLEN;
    __syncthreads();
    double s2 = 0.0;
    for (int i = t; i < TLEN; i += 256) { double d = (double)sx[i] - mean; s2 = fma(d, d, s2); }
    red[t] = s2; __syncthreads();
    for (int st = 128; st > 0; st >>= 1) { if (t < st) red[t] += red[t + st]; __syncthreads(); }
    if (t == 0) {
        double stdv = sqrt(red[0] / (double)TLEN + 1e-5);
        dws[DW_MEAN + b] = mean;
        dws[DW_RSTD + b] = 1.0 / stdv;
        ws[WS_FMEAN + b] = (float)mean;
        ws[WS_FSTD + b]  = (float)stdv;
    }
}

// ================= fused enc conv1 + conv2 (f64), quarter batch =================
__global__ __launch_bounds__(256) void fused12_kern(
        const float* __restrict__ x, const double* __restrict__ dws,
        double* __restrict__ out, int b0) {
    __shared__ double xt[262];
    __shared__ double s1e[64][65];   // y1[c, 2(l0+j)]
    __shared__ double s1o[64][65];   // y1[c, 2(l0+j)-1]
    __shared__ double lw1[256];
    __shared__ double lb1[64];
    const int bq = blockIdx.y;
    const int bg = b0 + bq;
    const int l0 = blockIdx.x * 64;
    const int tid = threadIdx.x;
    const double mean = dws[DW_MEAN + bg], rstd = dws[DW_RSTD + bg];
    const double* w2 = dws + DW_W2;
    const double* b2 = dws + DW_B2;

    if (tid < 256) lw1[tid] = dws[DW_W1 + tid];
    if (tid < 64)  lb1[tid] = dws[DW_B1 + tid];
    const int x_base = 4 * l0 - 3;
    const float* xb = x + (size_t)bg * TLEN;
    for (int i = tid; i < 262; i += 256) {
        int g = x_base + i;
        xt[i] = (g >= 0 && g < TLEN) ? ((double)xb[g] - mean) * rstd : 0.0;
    }
    __syncthreads();
    // conv1: m = 2*l0 - 1 + pp, pp in [0,130)
    for (int i = tid; i < 64 * 130; i += 256) {
        int o = i / 130, pp = i - o * 130;
        int m = 2 * l0 - 1 + pp;
        double val = 0.0;
        if (m >= 0 && m < LA) {
            double a = lb1[o];
            #pragma unroll
            for (int k = 0; k < 4; k++) a = fma(lw1[o * 4 + k], xt[2 * pp + k], a);
            val = a > 0.0 ? a : 0.0;
        }
        if ((pp & 1) == 0) s1o[o][pp >> 1] = val;        // pp even -> m odd
        else               s1e[o][(pp - 1) >> 1] = val;  // pp odd  -> m even
    }
    __syncthreads();
    const int lane = tid & 63;
    const int wave = tid >> 6;
    const int o0 = __builtin_amdgcn_readfirstlane(wave * 32);
    double acc[32];
    #pragma unroll
    for (int j = 0; j < 32; j++) acc[j] = b2[o0 + j];
    for (int c = 0; c < 64; c++) {
        double v0 = s1o[c][lane];
        double v1 = s1e[c][lane];
        double v2 = s1o[c][lane + 1];
        double v3 = s1e[c][lane + 1];
        #pragma unroll
        for (int j = 0; j < 32; j++) {
            const double* wp = w2 + ((size_t)(o0 + j) * 64 + c) * 4;
            double a = acc[j];
            a = fma(wp[0], v0, a);
            a = fma(wp[1], v1, a);
            a = fma(wp[2], v2, a);
            a = fma(wp[3], v3, a);
            acc[j] = a;
        }
    }
    #pragma unroll
    for (int j = 0; j < 32; j++) {
        double a = acc[j] > 0.0 ? acc[j] : 0.0;
        out[((size_t)bq * HID + o0 + j) * LB + l0 + lane] = a;
    }
}

// ================= generic f64 conv (quarter-local, L=2048, pad=K/2) =================
template<int CIN, int COUT, int K, bool RELU_IN, bool ADD_RES, bool HAS_BIAS>
__global__ __launch_bounds__(256) void conv64_kern(
        const double* __restrict__ in, const double* __restrict__ w,
        const double* __restrict__ bias, const double* res, double* out) {
    constexpr int W = 64 + K - 1;
    __shared__ double st[CIN * W];
    const int b = blockIdx.y;
    const int l0 = blockIdx.x * 64;
    const int tid = threadIdx.x;
    const double* inb = in + (size_t)b * CIN * LB;
    for (int i = tid; i < CIN * W; i += 256) {
        int c = i / W, p = i - c * W;
        int g = l0 + p - (K / 2);
        double v = 0.0;
        if (g >= 0 && g < LB) {
            v = inb[(size_t)c * LB + g];
            if (RELU_IN) v = v > 0.0 ? v : 0.0;
        }
        st[i] = v;
    }
    __syncthreads();
    const int lane = tid & 63;
    const int wave = tid >> 6;
    constexpr int OPW = COUT / 4;
    const int o0 = __builtin_amdgcn_readfirstlane(wave * OPW);
    const int l = l0 + lane;
    double acc[OPW];
    #pragma unroll
    for (int j = 0; j < OPW; j++) acc[j] = HAS_BIAS ? bias[o0 + j] : 0.0;
    for (int c = 0; c < CIN; c++) {
        double v[K];
        #pragma unroll
        for (int k = 0; k < K; k++) v[k] = st[c * W + lane + k];
        #pragma unroll
        for (int j = 0; j < OPW; j++) {
            const double* wp = w + ((size_t)(o0 + j) * CIN + c) * K;
            #pragma unroll
            for (int k = 0; k < K; k++) acc[j] = fma(wp[k], v[k], acc[j]);
        }
    }
    #pragma unroll
    for (int j = 0; j < OPW; j++) {
        double a = acc[j];
        if (ADD_RES) a += res[((size_t)b * COUT + o0 + j) * LB + l];
        out[((size_t)b * COUT + o0 + j) * LB + l] = a;
    }
}

// ================= VQ: replicate the reference's f32 arithmetic verbatim.
// d2[c] = (A - 2*dot(z,c)) + ||c||^2, ALL in f32, uncontracted, where
// A = ||z||^2 as mul-then-pairwise f32 sum (numpy order), dot = 8-chain FMA,
// z = correctly-rounded f32 of the exact (f64) encoder output.
// argmin with strict <, first (lowest) index wins — same as jnp/np.argmin.
// The comparison grid lives at ulp(A) (A >> code-dependent term), which is
// value-determined and shared across f32 implementations — this is why the
// jax and np references agree with each other, and we join that equivalence
// class instead of selecting on exact f64 distances (R1-R8 all failed there).
__global__ __launch_bounds__(256) void vq_kernel(
        const double* __restrict__ z64, const float* __restrict__ cbf,
        const float* __restrict__ cnorm,
        float* __restrict__ quant, float* __restrict__ idx_out,
        float* __restrict__ cnt, float* __restrict__ sse_acc, int b0) {
    __shared__ float s_m[4][64];
    __shared__ int   s_c[4][64];
    const int tid = threadIdx.x;
    const int tl = tid & 63;
    const int q = tid >> 6;
    const int nl = blockIdx.x * 64 + tl;         // local token in quarter
    const int bq = nl >> 11, l = nl & 2047;
    const int bg = b0 + bq;
    const double* zp = z64 + (size_t)bq * EMB * LB + l;
    float zv[EMB];
    #pragma unroll
    for (int d = 0; d < EMB; d++) zv[d] = (float)zp[(size_t)d * LB];

    // A = ||z||^2 : squares (rounded) then numpy-style 8-partial pairwise sum
    float p0=0,p1=0,p2=0,p3=0,p4=0,p5=0,p6=0,p7=0;
    #pragma unroll
    for (int d = 0; d < EMB; d += 8) {
        p0 = __fadd_rn(p0, __fmul_rn(zv[d],   zv[d]));
        p1 = __fadd_rn(p1, __fmul_rn(zv[d+1], zv[d+1]));
        p2 = __fadd_rn(p2, __fmul_rn(zv[d+2], zv[d+2]));
        p3 = __fadd_rn(p3, __fmul_rn(zv[d+3], zv[d+3]));
        p4 = __fadd_rn(p4, __fmul_rn(zv[d+4], zv[d+4]));
        p5 = __fadd_rn(p5, __fmul_rn(zv[d+5], zv[d+5]));
        p6 = __fadd_rn(p6, __fmul_rn(zv[d+6], zv[d+6]));
        p7 = __fadd_rn(p7, __fmul_rn(zv[d+7], zv[d+7]));
    }
    const float A = __fadd_rn(__fadd_rn(__fadd_rn(p0,p1), __fadd_rn(p2,p3)),
                              __fadd_rn(__fadd_rn(p4,p5), __fadd_rn(p6,p7)));

    float m1 = 1e30f; int c1 = 0;
    const int c0 = __builtin_amdgcn_readfirstlane(q * 128);
    for (int ci = 0; ci < 128; ci++) {
        const int c = c0 + ci;
        const float* wp = cbf + c * EMB;
        float d0=0,d1=0,d2=0,d3=0,d4=0,d5=0,d6=0,d7=0;
        #pragma unroll
        for (int d = 0; d < EMB; d += 8) {
            d0 = fmaf(wp[d],   zv[d],   d0);
            d1 = fmaf(wp[d+1], zv[d+1], d1);
            d2 = fmaf(wp[d+2], zv[d+2], d2);
            d3 = fmaf(wp[d+3], zv[d+3], d3);
            d4 = fmaf(wp[d+4], zv[d+4], d4);
            d5 = fmaf(wp[d+5], zv[d+5], d5);
            d6 = fmaf(wp[d+6], zv[d+6], d6);
            d7 = fmaf(wp[d+7], zv[d+7], d7);
        }
        float dot = __fadd_rn(__fadd_rn(__fadd_rn(d0,d1), __fadd_rn(d2,d3)),
                              __fadd_rn(__fadd_rn(d4,d5), __fadd_rn(d6,d7)));
        // (A - 2*dot) + cnorm — exactly the reference's left-to-right f32 ops
        float m = __fadd_rn(__fsub_rn(A, __fmul_rn(2.0f, dot)), cnorm[c]);
        if (m < m1) { m1 = m; c1 = c; }   // strict <: first index wins in-quarter
    }
    s_m[q][tl] = m1; s_c[q][tl] = c1;
    __syncthreads();
    if (q == 0) {
        float bm = s_m[0][tl]; int bc = s_c[0][tl];
        #pragma unroll
        for (int qq = 1; qq < 4; qq++) {
            float mm = s_m[qq][tl];
            if (mm < bm) { bm = mm; bc = s_c[qq][tl]; }  // ties keep earlier quarter = lower idx
        }
        idx_out[(size_t)bg * LB + l] = (float)bc;
        atomicAdd(&cnt[bc], 1.0f);
        float* qp = quant + (size_t)bg * EMB * LB + l;
        const float* cp = cbf + bc * EMB;
        float sse = 0.f;
        #pragma unroll
        for (int d = 0; d < EMB; d++) {
            float qv = cp[d];
            qp[(size_t)d * LB] = qv;
            float df = qv - zv[d];
            sse = fmaf(df, df, sse);
        }
        for (int off = 32; off > 0; off >>= 1) sse += __shfl_down(sse, off);
        if (tl == 0) atomicAdd(sse_acc, sse);
    }
}

// ================= decoder f32 conv (full batch, L=2048, pad=K/2) =================
template<int CIN, int COUT, int K, bool RELU_IN, bool RELU_OUT, bool ADD_RES, bool HAS_BIAS>
__global__ __launch_bounds__(256) void conv32_kern(
        const float* __restrict__ in, const float* __restrict__ w,
        const float* __restrict__ bias, const float* res, float* out) {
    constexpr int W = 64 + K - 1;
    __shared__ float st[CIN * W];
    const int b = blockIdx.y;
    const int l0 = blockIdx.x * 64;
    const int tid = threadIdx.x;
    const float* inb = in + (size_t)b * CIN * LB;
    for (int i = tid; i < CIN * W; i += 256) {
        int c = i / W, p = i - c * W;
        int g = l0 + p - (K / 2);
        float v = 0.f;
        if (g >= 0 && g < LB) {
            v = inb[(size_t)c * LB + g];
            if (RELU_IN) v = fmaxf(v, 0.f);
        }
        st[i] = v;
    }
    __syncthreads();
    const int lane = tid & 63;
    const int wave = tid >> 6;
    constexpr int OPW = COUT / 4;
    constexpr int NO = OPW < 16 ? OPW : 16;
    const int l = l0 + lane;
    for (int oc = 0; oc < OPW; oc += NO) {
        const int o0 = __builtin_amdgcn_readfirstlane(wave * OPW + oc);
        float acc[NO];
        #pragma unroll
        for (int j = 0; j < NO; j++) acc[j] = HAS_BIAS ? bias[o0 + j] : 0.f;
        for (int c = 0; c < CIN; c++) {
            float v[K];
            #pragma unroll
            for (int k = 0; k < K; k++) v[k] = st[c * W + lane + k];
            #pragma unroll
            for (int j = 0; j < NO; j++) {
                #pragma unroll
                for (int k = 0; k < K; k++)
                    acc[j] = fmaf(w[((o0 + j) * CIN + c) * K + k], v[k], acc[j]);
            }
        }
        #pragma unroll
        for (int j = 0; j < NO; j++) {
            float a = acc[j];
            if (ADD_RES) a += res[((size_t)b * COUT + o0 + j) * LB + l];
            if (RELU_OUT) a = fmaxf(a, 0.f);
            out[((size_t)b * COUT + o0 + j) * LB + l] = a;
        }
    }
}

// ================= ConvTranspose1d (f32 decoder) =================
__global__ __launch_bounds__(256) void convt1_kern(const float* __restrict__ in,
        const float* __restrict__ w, const float* __restrict__ bias, float* out) {
    __shared__ float s_in[HID * 66];
    const int b = blockIdx.y;
    const int t0 = blockIdx.x * 128;
    const int m0 = t0 / 2 - 1;
    const int tid = threadIdx.x;
    const float* inb = in + (size_t)b * HID * LB;
    for (int i = tid; i < HID * 66; i += 256) {
        int c = i / 66, p = i - c * 66;
        int m = m0 + p;
        s_in[i] = (m >= 0 && m < LB) ? fmaxf(inb[(size_t)c * LB + m], 0.f) : 0.f;
    }
    __syncthreads();
    const int lane = tid & 63;
    const int wave = tid >> 6;
    const int o0 = __builtin_amdgcn_readfirstlane(wave * 16);
    float accE[16], accO[16];
    #pragma unroll
    for (int j = 0; j < 16; j++) { float bv = bias[o0 + j]; accE[j] = bv; accO[j] = bv; }
    for (int c = 0; c < HID; c++) {
        float v0 = s_in[c * 66 + lane];
        float v1 = s_in[c * 66 + lane + 1];
        float v2 = s_in[c * 66 + lane + 2];
        #pragma unroll
        for (int j = 0; j < 16; j++) {
            const float* wc = w + ((size_t)c * HHALF + o0 + j) * 4;
            accE[j] = fmaf(wc[1], v1, fmaf(wc[3], v0, accE[j]));
            accO[j] = fmaf(wc[0], v2, fmaf(wc[2], v1, accO[j]));
        }
    }
    #pragma unroll
    for (int j = 0; j < 16; j++) {
        float2 pr;
        pr.x = fmaxf(accE[j], 0.f);
        pr.y = fmaxf(accO[j], 0.f);
        *(float2*)&out[((size_t)b * HHALF + o0 + j) * LA + t0 + 2 * lane] = pr;
    }
}

__global__ __launch_bounds__(256) void convt2_kern(const float* __restrict__ in,
        const float* __restrict__ w, const float* __restrict__ bias,
        const float* __restrict__ mstats, float* out) {
    __shared__ float s_in[16 * 258];
    const int b = blockIdx.y;
    const int t0 = blockIdx.x * 512;
    const int m0 = t0 / 2 - 1;
    const int tid = threadIdx.x;
    const float* inb = in + (size_t)b * HHALF * LA;
    float accE = 0.f, accO = 0.f;
    for (int cg = 0; cg < 4; cg++) {
        __syncthreads();
        for (int i = tid; i < 16 * 258; i += 256) {
            int c = i / 258, p = i - c * 258;
            int m = m0 + p;
            s_in[i] = (m >= 0 && m < LA) ? inb[(size_t)(cg * 16 + c) * LA + m] : 0.f;
        }
        __syncthreads();
        for (int c = 0; c < 16; c++) {
            float v0 = s_in[c * 258 + tid];
            float v1 = s_in[c * 258 + tid + 1];
            float v2 = s_in[c * 258 + tid + 2];
            const float* wc = w + (size_t)(cg * 16 + c) * 4;
            accE = fmaf(wc[1], v1, fmaf(wc[3], v0, accE));
            accO = fmaf(wc[0], v2, fmaf(wc[2], v1, accO));
        }
    }
    const float mean = mstats[WS_FMEAN + b], stdv = mstats[WS_FSTD + b];
    const float b0 = bias[0];
    float2 pr;
    pr.x = (accE + b0) * stdv + mean;
    pr.y = (accO + b0) * stdv + mean;
    *(float2*)&out[(size_t)b * TLEN + t0 + 2 * tid] = pr;
}

// ================= finalize =================
__global__ __launch_bounds__(512) void finalize_kernel(const float* cnt, const float* sse,
                                                       float* d_out) {
    __shared__ float red[512];
    const int t = threadIdx.x;
    float n = cnt[t];
    float p = n / (float)NTOK;
    red[t] = -p * logf(p + 1e-10f);
    __syncthreads();
    for (int s = 256; s > 0; s >>= 1) { if (t < s) red[t] += red[t + s]; __syncthreads(); }
    if (t == 0) {
        d_out[(size_t)NBATCH * TLEN] = sse[0] * 1.25f / (float)((size_t)NTOK * EMB);
        d_out[(size_t)NBATCH * TLEN + 1 + NTOK] = expf(red[0]);
    }
}

// ================= launcher =================
extern "C" void kernel_launch(void* const* d_in, const int* in_sizes, int n_in,
                              void* d_out, int out_size, void* d_ws, size_t ws_size,
                              hipStream_t stream) {
    (void)in_sizes; (void)n_in; (void)out_size; (void)ws_size;

    const float* x         = (const float*)d_in[0];
    const float* enc_w1    = (const float*)d_in[1];
    const float* enc_b1    = (const float*)d_in[2];
    const float* enc_w2    = (const float*)d_in[3];
    const float* enc_b2    = (const float*)d_in[4];
    const float* enc_w3    = (const float*)d_in[5];
    const float* enc_b3    = (const float*)d_in[6];
    const float* enc_rw1   = (const float*)d_in[7];
    const float* enc_rw2   = (const float*)d_in[8];
    const float* enc_pre_w = (const float*)d_in[9];
    const float* enc_pre_b = (const float*)d_in[10];
    const float* codebook  = (const float*)d_in[11];
    const float* dec_w1    = (const float*)d_in[12];
    const float* dec_b1    = (const float*)d_in[13];
    const float* dec_rw1   = (const float*)d_in[14];
    const float* dec_rw2   = (const float*)d_in[15];
    const float* dec_t1_w  = (const float*)d_in[16];
    const float* dec_t1_b  = (const float*)d_in[17];
    const float* dec_t2_w  = (const float*)d_in[18];
    const float* dec_t2_b  = (const float*)d_in[19];

    float*  ws  = (float*)d_ws;
    double* dws = (double*)d_ws;
    char*   wsb = (char*)d_ws;
    float*  out = (float*)d_out;

    float*  QUANT = (float*)(wsb + OFF_QUANT);
    double* D2Q   = (double*)(wsb + OFF_D2Q);
    double* D3Q   = (double*)(wsb + OFF_D3Q);
    double* S64Q  = (double*)(wsb + OFF_S64Q);
    double* Z64Q  = (double*)(wsb + OFF_Z64Q);
    float*  A32   = (float*)(wsb + OFF_A32);
    float*  S32   = (float*)(wsb + OFF_S32);
    float*  B32   = (float*)(wsb + OFF_B32);
    float*  idx_out = out + (size_t)NBATCH * TLEN + 1;

    // weights -> f64
    cvt_kernel<<<1, 256, 0, stream>>>(enc_w1, dws + DW_W1, 256);
    cvt_kernel<<<1, 256, 0, stream>>>(enc_b1, dws + DW_B1, 64);
    cvt_kernel<<<128, 256, 0, stream>>>(enc_w2, dws + DW_W2, 32768);
    cvt_kernel<<<1, 256, 0, stream>>>(enc_b2, dws + DW_B2, 128);
    cvt_kernel<<<192, 256, 0, stream>>>(enc_w3, dws + DW_W3, 49152);
    cvt_kernel<<<1, 256, 0, stream>>>(enc_b3, dws + DW_B3, 128);
    cvt_kernel<<<96, 256, 0, stream>>>(enc_rw1, dws + DW_RW1, 24576);
    cvt_kernel<<<32, 256, 0, stream>>>(enc_rw2, dws + DW_RW2, 8192);
    cvt_kernel<<<32, 256, 0, stream>>>(enc_pre_w, dws + DW_PW, 8192);
    cvt_kernel<<<1, 256, 0, stream>>>(enc_pre_b, dws + DW_PB, 64);

    zero_kernel<<<1, 1024, 0, stream>>>(ws + WS_CNT, 513);
    cnorm_kernel<<<2, 256, 0, stream>>>(codebook, ws + WS_CNORM);
    stats_kernel<<<NBATCH, 256, 0, stream>>>(x, dws, ws);

    // ---- encoder + VQ in 4 batch-quarters (f64) ----
    for (int qq = 0; qq < 4; qq++) {
        const int b0 = qq * NQB;
        fused12_kern<<<dim3(LB / 64, NQB), 256, 0, stream>>>(x, dws, D2Q, b0);
        conv64_kern<128, 128, 3, false, false, true>
            <<<dim3(LB / 64, NQB), 256, 0, stream>>>(D2Q, dws + DW_W3, dws + DW_B3, nullptr, D3Q);
        for (int i = 0; i < 2; i++) {
            conv64_kern<128, 32, 3, true, false, false>
                <<<dim3(LB / 64, NQB), 256, 0, stream>>>(D3Q, dws + DW_RW1 + (size_t)i * 12288,
                                                         nullptr, nullptr, S64Q);
            conv64_kern<32, 128, 1, true, true, false>
                <<<dim3(LB / 64, NQB), 256, 0, stream>>>(S64Q, dws + DW_RW2 + (size_t)i * 4096,
                                                         nullptr, D3Q, D3Q);
        }
        conv64_kern<128, 64, 1, true, false, true>
            <<<dim3(LB / 64, NQB), 256, 0, stream>>>(D3Q, dws + DW_PW, dws + DW_PB, nullptr, Z64Q);
        vq_kernel<<<(NQB * LB) / 64, 256, 0, stream>>>(Z64Q, codebook, ws + WS_CNORM,
                                                       QUANT, idx_out, ws + WS_CNT, ws + WS_SSE, b0);
    }

    // ---- decoder (f32, full batch) ----
    conv32_kern<64, 128, 3, false, false, false, true>
        <<<dim3(LB / 64, NBATCH), 256, 0, stream>>>(QUANT, dec_w1, dec_b1, nullptr, A32);
    for (int i = 0; i < 2; i++) {
        conv32_kern<128, 32, 3, true, false, false, false>
            <<<dim3(LB / 64, NBATCH), 256, 0, stream>>>(A32, dec_rw1 + (size_t)i * RESCH * HID * 3,
                                                        nullptr, nullptr, S32);
        conv32_kern<32, 128, 1, true, false, true, false>
            <<<dim3(LB / 64, NBATCH), 256, 0, stream>>>(S32, dec_rw2 + (size_t)i * HID * RESCH,
                                                        nullptr, A32, A32);
    }
    convt1_kern<<<dim3(LA / 128, NBATCH), 256, 0, stream>>>(A32, dec_t1_w, dec_t1_b, B32);
    convt2_kern<<<dim3(TLEN / 512, NBATCH), 256, 0, stream>>>(B32, dec_t2_w, dec_t2_b, ws, out);

    finalize_kernel<<<1, 512, 0, stream>>>(ws + WS_CNT, ws + WS_SSE, out);
}

// Round 10
// 3438.707 us; speedup vs baseline: 1.2389x; 1.2389x over previous
//
#include <hip/hip_runtime.h>
#include <cmath>

// ---------------- problem constants ----------------
#define NBATCH 64
#define TLEN   8192
#define LA     4096
#define LB     2048
#define HID    128
#define HHALF  64
#define RESCH  32
#define EMB    64
#define NCODE  512
#define NTOK   (NBATCH * LB)   // 131072

// ---------------- ws layout (float offsets; end = 151,011,328 bytes, verified R1) ----
#define WS_MEAN  0       // 64  f32 mean
#define WS_RSTD  64      // 64  f32 1/std
#define WS_STD   128     // 64  f32 std (denorm)
#define WS_CNORM 192     // 512
#define WS_CNT   704     // 512
#define WS_SSE   1216    // 1
#define WS_A     4096                    // f32 [64][128][2048] = 16,777,216 floats
#define WS_B     (WS_A + 16777216)       // z [64][64][2048] + quant [64][64][2048]
#define WS_S     (WS_B + 16777216)       // f32 [64][32][2048] = 4,194,304 floats

// ================= tiny kernels =================

__global__ __launch_bounds__(1024) void zero_kernel(float* p, int n) {
    int i = blockIdx.x * 1024 + threadIdx.x;
    if (i < n) p[i] = 0.f;
}

// ||c||^2 in f32, numpy-pairwise style: squares (rounded muls) then 8-partial sum
__global__ __launch_bounds__(256) void cnorm_kernel(const float* __restrict__ cb,
                                                    float* __restrict__ cnorm) {
    int k = blockIdx.x * 256 + threadIdx.x;
    if (k < NCODE) {
        float p0=0,p1=0,p2=0,p3=0,p4=0,p5=0,p6=0,p7=0;
        const float* cp = cb + k * EMB;
        #pragma unroll
        for (int d = 0; d < EMB; d += 8) {
            p0 = __fadd_rn(p0, __fmul_rn(cp[d],   cp[d]));
            p1 = __fadd_rn(p1, __fmul_rn(cp[d+1], cp[d+1]));
            p2 = __fadd_rn(p2, __fmul_rn(cp[d+2], cp[d+2]));
            p3 = __fadd_rn(p3, __fmul_rn(cp[d+3], cp[d+3]));
            p4 = __fadd_rn(p4, __fmul_rn(cp[d+4], cp[d+4]));
            p5 = __fadd_rn(p5, __fmul_rn(cp[d+5], cp[d+5]));
            p6 = __fadd_rn(p6, __fmul_rn(cp[d+6], cp[d+6]));
            p7 = __fadd_rn(p7, __fmul_rn(cp[d+7], cp[d+7]));
        }
        float s01 = __fadd_rn(p0, p1), s23 = __fadd_rn(p2, p3);
        float s45 = __fadd_rn(p4, p5), s67 = __fadd_rn(p6, p7);
        cnorm[k] = __fadd_rn(__fadd_rn(s01, s23), __fadd_rn(s45, s67));
    }
}

// per-batch mean/std over T=8192 (f64 internal; f32 outputs — refs' noise class)
__global__ __launch_bounds__(256) void stats_kernel(const float* __restrict__ x, float* ws) {
    __shared__ float sx[TLEN];
    __shared__ double red[256];
    const int b = blockIdx.x, t = threadIdx.x;
    const float* xb = x + (size_t)b * TLEN;
    double s = 0.0;
    for (int i = t; i < TLEN; i += 256) { float v = xb[i]; sx[i] = v; s += (double)v; }
    red[t] = s; __syncthreads();
    for (int st = 128; st > 0; st >>= 1) { if (t < st) red[t] += red[t + st]; __syncthreads(); }
    double mean = red[0] / (double)TLEN;
    __syncthreads();
    double s2 = 0.0;
    for (int i = t; i < TLEN; i += 256) { double d = (double)sx[i] - mean; s2 = fma(d, d, s2); }
    red[t] = s2; __syncthreads();
    for (int st = 128; st > 0; st >>= 1) { if (t < st) red[t] += red[t + st]; __syncthreads(); }
    if (t == 0) {
        double stdv = sqrt(red[0] / (double)TLEN + 1e-5);
        ws[WS_MEAN + b] = (float)mean;
        ws[WS_RSTD + b] = (float)(1.0 / stdv);
        ws[WS_STD + b]  = (float)stdv;
    }
}

// ================= fused enc conv1 + conv2 (f32, full batch) =================
// conv1: 1->64 K4 S2 P1 relu on normalized x; conv2: 64->128 K4 S2 P1 relu.
__global__ __launch_bounds__(256) void fused12_kern(
        const float* __restrict__ x, const float* __restrict__ w1g,
        const float* __restrict__ b1g, const float* __restrict__ w2,
        const float* __restrict__ b2, const float* __restrict__ ws,
        float* __restrict__ out) {
    __shared__ float xt[262];
    __shared__ float s1e[64][65];   // y1[c, 2(l0+j)]
    __shared__ float s1o[64][65];   // y1[c, 2(l0+j)-1]
    __shared__ float lw1[256];
    __shared__ float lb1[64];
    const int b = blockIdx.y;
    const int l0 = blockIdx.x * 64;
    const int tid = threadIdx.x;
    const float mean = ws[WS_MEAN + b], stdv = ws[WS_STD + b];

    if (tid < 256) lw1[tid] = w1g[tid];
    if (tid < 64)  lb1[tid] = b1g[tid];
    const int x_base = 4 * l0 - 3;
    const float* xb = x + (size_t)b * TLEN;
    for (int i = tid; i < 262; i += 256) {
        int g = x_base + i;
        xt[i] = (g >= 0 && g < TLEN) ? (xb[g] - mean) / stdv : 0.f;
    }
    __syncthreads();
    // conv1: m = 2*l0 - 1 + pp, pp in [0,130)
    for (int i = tid; i < 64 * 130; i += 256) {
        int o = i / 130, pp = i - o * 130;
        int m = 2 * l0 - 1 + pp;
        float val = 0.f;
        if (m >= 0 && m < LA) {
            float a = lb1[o];
            #pragma unroll
            for (int k = 0; k < 4; k++) a = fmaf(lw1[o * 4 + k], xt[2 * pp + k], a);
            val = fmaxf(a, 0.f);
        }
        if ((pp & 1) == 0) s1o[o][pp >> 1] = val;        // pp even -> m odd
        else               s1e[o][(pp - 1) >> 1] = val;  // pp odd  -> m even
    }
    __syncthreads();
    const int lane = tid & 63;
    const int wave = tid >> 6;
    const int o0 = __builtin_amdgcn_readfirstlane(wave * 32);
    float acc[32];
    #pragma unroll
    for (int j = 0; j < 32; j++) acc[j] = b2[o0 + j];
    for (int c = 0; c < 64; c++) {
        float v0 = s1o[c][lane];
        float v1 = s1e[c][lane];
        float v2 = s1o[c][lane + 1];
        float v3 = s1e[c][lane + 1];
        #pragma unroll
        for (int j = 0; j < 32; j++) {
            const float* wp = w2 + ((size_t)(o0 + j) * 64 + c) * 4;
            float a = acc[j];
            a = fmaf(wp[0], v0, a);
            a = fmaf(wp[1], v1, a);
            a = fmaf(wp[2], v2, a);
            a = fmaf(wp[3], v3, a);
            acc[j] = a;
        }
    }
    #pragma unroll
    for (int j = 0; j < 32; j++)
        out[((size_t)b * HID + o0 + j) * LB + l0 + lane] = fmaxf(acc[j], 0.f);
}

// ================= generic f32 conv (full batch, L=2048, pad=K/2) =================
template<int CIN, int COUT, int K, bool RELU_IN, bool RELU_OUT, bool ADD_RES, bool HAS_BIAS>
__global__ __launch_bounds__(256) void conv32_kern(
        const float* __restrict__ in, const float* __restrict__ w,
        const float* __restrict__ bias, const float* res, float* out) {
    constexpr int W = 64 + K - 1;
    __shared__ float st[CIN * W];
    const int b = blockIdx.y;
    const int l0 = blockIdx.x * 64;
    const int tid = threadIdx.x;
    const float* inb = in + (size_t)b * CIN * LB;
    for (int i = tid; i < CIN * W; i += 256) {
        int c = i / W, p = i - c * W;
        int g = l0 + p - (K / 2);
        float v = 0.f;
        if (g >= 0 && g < LB) {
            v = inb[(size_t)c * LB + g];
            if (RELU_IN) v = fmaxf(v, 0.f);
        }
        st[i] = v;
    }
    __syncthreads();
    const int lane = tid & 63;
    const int wave = tid >> 6;
    constexpr int OPW = COUT / 4;
    constexpr int NO = OPW < 16 ? OPW : 16;
    const int l = l0 + lane;
    for (int oc = 0; oc < OPW; oc += NO) {
        const int o0 = __builtin_amdgcn_readfirstlane(wave * OPW + oc);
        float acc[NO];
        #pragma unroll
        for (int j = 0; j < NO; j++) acc[j] = HAS_BIAS ? bias[o0 + j] : 0.f;
        for (int c = 0; c < CIN; c++) {
            float v[K];
            #pragma unroll
            for (int k = 0; k < K; k++) v[k] = st[c * W + lane + k];
            #pragma unroll
            for (int j = 0; j < NO; j++) {
                #pragma unroll
                for (int k = 0; k < K; k++)
                    acc[j] = fmaf(w[((o0 + j) * CIN + c) * K + k], v[k], acc[j]);
            }
        }
        #pragma unroll
        for (int j = 0; j < NO; j++) {
            float a = acc[j];
            if (ADD_RES) a += res[((size_t)b * COUT + o0 + j) * LB + l];
            if (RELU_OUT) a = fmaxf(a, 0.f);
            out[((size_t)b * COUT + o0 + j) * LB + l] = a;
        }
    }
}

// ================= VQ: reference's f32 arithmetic verbatim (R9-verified), full batch.
// d2[c] = (A - 2*dot(z,c)) + ||c||^2 all f32 uncontracted; A,cnorm = mul+pairwise;
// dot = 8-chain FMA; argmin strict <, lowest index wins.
__global__ __launch_bounds__(256) void vq_kernel(
        const float* __restrict__ z, const float* __restrict__ cbf,
        const float* __restrict__ cnorm,
        float* __restrict__ quant, float* __restrict__ idx_out,
        float* __restrict__ cnt, float* __restrict__ sse_acc) {
    __shared__ float s_m[4][64];
    __shared__ int   s_c[4][64];
    const int tid = threadIdx.x;
    const int tl = tid & 63;
    const int q = tid >> 6;
    const int n = blockIdx.x * 64 + tl;
    const int b = n >> 11, l = n & 2047;
    const float* zp = z + (size_t)b * EMB * LB + l;
    float zv[EMB];
    #pragma unroll
    for (int d = 0; d < EMB; d++) zv[d] = zp[(size_t)d * LB];

    // A = ||z||^2 : squares (rounded) then numpy-style 8-partial pairwise sum
    float p0=0,p1=0,p2=0,p3=0,p4=0,p5=0,p6=0,p7=0;
    #pragma unroll
    for (int d = 0; d < EMB; d += 8) {
        p0 = __fadd_rn(p0, __fmul_rn(zv[d],   zv[d]));
        p1 = __fadd_rn(p1, __fmul_rn(zv[d+1], zv[d+1]));
        p2 = __fadd_rn(p2, __fmul_rn(zv[d+2], zv[d+2]));
        p3 = __fadd_rn(p3, __fmul_rn(zv[d+3], zv[d+3]));
        p4 = __fadd_rn(p4, __fmul_rn(zv[d+4], zv[d+4]));
        p5 = __fadd_rn(p5, __fmul_rn(zv[d+5], zv[d+5]));
        p6 = __fadd_rn(p6, __fmul_rn(zv[d+6], zv[d+6]));
        p7 = __fadd_rn(p7, __fmul_rn(zv[d+7], zv[d+7]));
    }
    const float A = __fadd_rn(__fadd_rn(__fadd_rn(p0,p1), __fadd_rn(p2,p3)),
                              __fadd_rn(__fadd_rn(p4,p5), __fadd_rn(p6,p7)));

    float m1 = 1e30f; int c1 = 0;
    const int c0 = __builtin_amdgcn_readfirstlane(q * 128);
    for (int ci = 0; ci < 128; ci++) {
        const int c = c0 + ci;
        const float* wp = cbf + c * EMB;
        float d0=0,d1=0,d2=0,d3=0,d4=0,d5=0,d6=0,d7=0;
        #pragma unroll
        for (int d = 0; d < EMB; d += 8) {
            d0 = fmaf(wp[d],   zv[d],   d0);
            d1 = fmaf(wp[d+1], zv[d+1], d1);
            d2 = fmaf(wp[d+2], zv[d+2], d2);
            d3 = fmaf(wp[d+3], zv[d+3], d3);
            d4 = fmaf(wp[d+4], zv[d+4], d4);
            d5 = fmaf(wp[d+5], zv[d+5], d5);
            d6 = fmaf(wp[d+6], zv[d+6], d6);
            d7 = fmaf(wp[d+7], zv[d+7], d7);
        }
        float dot = __fadd_rn(__fadd_rn(__fadd_rn(d0,d1), __fadd_rn(d2,d3)),
                              __fadd_rn(__fadd_rn(d4,d5), __fadd_rn(d6,d7)));
        float m = __fadd_rn(__fsub_rn(A, __fmul_rn(2.0f, dot)), cnorm[c]);
        if (m < m1) { m1 = m; c1 = c; }   // strict <: first index wins in-quarter
    }
    s_m[q][tl] = m1; s_c[q][tl] = c1;
    __syncthreads();
    if (q == 0) {
        float bm = s_m[0][tl]; int bc = s_c[0][tl];
        #pragma unroll
        for (int qq = 1; qq < 4; qq++) {
            float mm = s_m[qq][tl];
            if (mm < bm) { bm = mm; bc = s_c[qq][tl]; }  // ties keep earlier quarter = lower idx
        }
        idx_out[n] = (float)bc;
        atomicAdd(&cnt[bc], 1.0f);
        float* qp = quant + (size_t)b * EMB * LB + l;
        const float* cp = cbf + bc * EMB;
        float sse = 0.f;
        #pragma unroll
        for (int d = 0; d < EMB; d++) {
            float qv = cp[d];
            qp[(size_t)d * LB] = qv;
            float df = qv - zv[d];
            sse = fmaf(df, df, sse);
        }
        for (int off = 32; off > 0; off >>= 1) sse += __shfl_down(sse, off);
        if (tl == 0) atomicAdd(sse_acc, sse);
    }
}

// ================= ConvTranspose1d (f32 decoder) =================
__global__ __launch_bounds__(256) void convt1_kern(const float* __restrict__ in,
        const float* __restrict__ w, const float* __restrict__ bias, float* out) {
    __shared__ float s_in[HID * 66];
    const int b = blockIdx.y;
    const int t0 = blockIdx.x * 128;
    const int m0 = t0 / 2 - 1;
    const int tid = threadIdx.x;
    const float* inb = in + (size_t)b * HID * LB;
    for (int i = tid; i < HID * 66; i += 256) {
        int c = i / 66, p = i - c * 66;
        int m = m0 + p;
        s_in[i] = (m >= 0 && m < LB) ? fmaxf(inb[(size_t)c * LB + m], 0.f) : 0.f;
    }
    __syncthreads();
    const int lane = tid & 63;
    const int wave = tid >> 6;
    const int o0 = __builtin_amdgcn_readfirstlane(wave * 16);
    float accE[16], accO[16];
    #pragma unroll
    for (int j = 0; j < 16; j++) { float bv = bias[o0 + j]; accE[j] = bv; accO[j] = bv; }
    for (int c = 0; c < HID; c++) {
        float v0 = s_in[c * 66 + lane];
        float v1 = s_in[c * 66 + lane + 1];
        float v2 = s_in[c * 66 + lane + 2];
        #pragma unroll
        for (int j = 0; j < 16; j++) {
            const float* wc = w + ((size_t)c * HHALF + o0 + j) * 4;
            accE[j] = fmaf(wc[1], v1, fmaf(wc[3], v0, accE[j]));
            accO[j] = fmaf(wc[0], v2, fmaf(wc[2], v1, accO[j]));
        }
    }
    #pragma unroll
    for (int j = 0; j < 16; j++) {
        float2 pr;
        pr.x = fmaxf(accE[j], 0.f);
        pr.y = fmaxf(accO[j], 0.f);
        *(float2*)&out[((size_t)b * HHALF + o0 + j) * LA + t0 + 2 * lane] = pr;
    }
}

__global__ __launch_bounds__(256) void convt2_kern(const float* __restrict__ in,
        const float* __restrict__ w, const float* __restrict__ bias,
        const float* __restrict__ mstats, float* out) {
    __shared__ float s_in[16 * 258];
    const int b = blockIdx.y;
    const int t0 = blockIdx.x * 512;
    const int m0 = t0 / 2 - 1;
    const int tid = threadIdx.x;
    const float* inb = in + (size_t)b * HHALF * LA;
    float accE = 0.f, accO = 0.f;
    for (int cg = 0; cg < 4; cg++) {
        __syncthreads();
        for (int i = tid; i < 16 * 258; i += 256) {
            int c = i / 258, p = i - c * 258;
            int m = m0 + p;
            s_in[i] = (m >= 0 && m < LA) ? inb[(size_t)(cg * 16 + c) * LA + m] : 0.f;
        }
        __syncthreads();
        for (int c = 0; c < 16; c++) {
            float v0 = s_in[c * 258 + tid];
            float v1 = s_in[c * 258 + tid + 1];
            float v2 = s_in[c * 258 + tid + 2];
            const float* wc = w + (size_t)(cg * 16 + c) * 4;
            accE = fmaf(wc[1], v1, fmaf(wc[3], v0, accE));
            accO = fmaf(wc[0], v2, fmaf(wc[2], v1, accO));
        }
    }
    const float mean = mstats[WS_MEAN + b], stdv = mstats[WS_STD + b];
    const float b0 = bias[0];
    float2 pr;
    pr.x = (accE + b0) * stdv + mean;
    pr.y = (accO + b0) * stdv + mean;
    *(float2*)&out[(size_t)b * TLEN + t0 + 2 * tid] = pr;
}

// ================= finalize =================
__global__ __launch_bounds__(512) void finalize_kernel(const float* cnt, const float* sse,
                                                       float* d_out) {
    __shared__ float red[512];
    const int t = threadIdx.x;
    float n = cnt[t];
    float p = n / (float)NTOK;
    red[t] = -p * logf(p + 1e-10f);
    __syncthreads();
    for (int s = 256; s > 0; s >>= 1) { if (t < s) red[t] += red[t + s]; __syncthreads(); }
    if (t == 0) {
        d_out[(size_t)NBATCH * TLEN] = sse[0] * 1.25f / (float)((size_t)NTOK * EMB);
        d_out[(size_t)NBATCH * TLEN + 1 + NTOK] = expf(red[0]);
    }
}

// ================= launcher =================
extern "C" void kernel_launch(void* const* d_in, const int* in_sizes, int n_in,
                              void* d_out, int out_size, void* d_ws, size_t ws_size,
                              hipStream_t stream) {
    (void)in_sizes; (void)n_in; (void)out_size; (void)ws_size;

    const float* x         = (const float*)d_in[0];
    const float* enc_w1    = (const float*)d_in[1];
    const float* enc_b1    = (const float*)d_in[2];
    const float* enc_w2    = (const float*)d_in[3];
    const float* enc_b2    = (const float*)d_in[4];
    const float* enc_w3    = (const float*)d_in[5];
    const float* enc_b3    = (const float*)d_in[6];
    const float* enc_rw1   = (const float*)d_in[7];
    const float* enc_rw2   = (const float*)d_in[8];
    const float* enc_pre_w = (const float*)d_in[9];
    const float* enc_pre_b = (const float*)d_in[10];
    const float* codebook  = (const float*)d_in[11];
    const float* dec_w1    = (const float*)d_in[12];
    const float* dec_b1    = (const float*)d_in[13];
    const float* dec_rw1   = (const float*)d_in[14];
    const float* dec_rw2   = (const float*)d_in[15];
    const float* dec_t1_w  = (const float*)d_in[16];
    const float* dec_t1_b  = (const float*)d_in[17];
    const float* dec_t2_w  = (const float*)d_in[18];
    const float* dec_t2_b  = (const float*)d_in[19];

    float* ws  = (float*)d_ws;
    float* out = (float*)d_out;
    float* A   = ws + WS_A;
    float* Bb  = ws + WS_B;
    float* S   = ws + WS_S;
    float* z     = Bb;
    float* quant = Bb + (size_t)NBATCH * EMB * LB;     // second half of B
    float* idx_out = out + (size_t)NBATCH * TLEN + 1;

    zero_kernel<<<1, 1024, 0, stream>>>(ws + WS_CNT, 513);
    cnorm_kernel<<<2, 256, 0, stream>>>(codebook, ws + WS_CNORM);
    stats_kernel<<<NBATCH, 256, 0, stream>>>(x, ws);

    // ---- encoder (f32, full batch) ----
    fused12_kern<<<dim3(LB / 64, NBATCH), 256, 0, stream>>>(x, enc_w1, enc_b1,
                                                            enc_w2, enc_b2, ws, Bb);
    conv32_kern<128, 128, 3, false, false, false, true>
        <<<dim3(LB / 64, NBATCH), 256, 0, stream>>>(Bb, enc_w3, enc_b3, nullptr, A);
    for (int i = 0; i < 2; i++) {
        conv32_kern<128, 32, 3, true, false, false, false>
            <<<dim3(LB / 64, NBATCH), 256, 0, stream>>>(A, enc_rw1 + (size_t)i * RESCH * HID * 3,
                                                        nullptr, nullptr, S);
        conv32_kern<32, 128, 1, true, false, true, false>
            <<<dim3(LB / 64, NBATCH), 256, 0, stream>>>(S, enc_rw2 + (size_t)i * HID * RESCH,
                                                        nullptr, A, A);
    }
    conv32_kern<128, 64, 1, true, false, false, true>
        <<<dim3(LB / 64, NBATCH), 256, 0, stream>>>(A, enc_pre_w, enc_pre_b, nullptr, z);

    // ---- VQ (full batch, one dispatch) ----
    vq_kernel<<<NTOK / 64, 256, 0, stream>>>(z, codebook, ws + WS_CNORM,
                                             quant, idx_out, ws + WS_CNT, ws + WS_SSE);

    // ---- decoder (f32) ----
    conv32_kern<64, 128, 3, false, false, false, true>
        <<<dim3(LB / 64, NBATCH), 256, 0, stream>>>(quant, dec_w1, dec_b1, nullptr, A);
    for (int i = 0; i < 2; i++) {
        conv32_kern<128, 32, 3, true, false, false, false>
            <<<dim3(LB / 64, NBATCH), 256, 0, stream>>>(A, dec_rw1 + (size_t)i * RESCH * HID * 3,
                                                        nullptr, nullptr, S);
        conv32_kern<32, 128, 1, true, false, true, false>
            <<<dim3(LB / 64, NBATCH), 256, 0, stream>>>(S, dec_rw2 + (size_t)i * HID * RESCH,
                                                        nullptr, A, A);
    }
    convt1_kern<<<dim3(LA / 128, NBATCH), 256, 0, stream>>>(A, dec_t1_w, dec_t1_b, Bb);
    convt2_kern<<<dim3(TLEN / 512, NBATCH), 256, 0, stream>>>(Bb, dec_t2_w, dec_t2_b, ws, out);

    finalize_kernel<<<1, 512, 0, stream>>>(ws + WS_CNT, ws + WS_SSE, out);
}